// Round 6
// baseline (5057.617 us; speedup 1.0000x reference)
//
#include <hip/hip_runtime.h>
#include <math.h>

#define D 64
#define R 5
#define EPT 4              // edges per thread: each scalar P value feeds 4 FMAs
#define BLOCK 256
#define EPB (EPT * BLOCK)
#define FH 32              // f-phase half width (vs regs = EPT*FH = 128)

// minwaves MUST stay 2: (256,4) caps at 64 VGPR and spills (R3: 14 GB thrash).
__global__ __launch_bounds__(BLOCK, 2)
void bidecoder_kernel(const float* __restrict__ ufeat,
                      const float* __restrict__ ifeat,
                      const float* __restrict__ Ps,
                      const int* __restrict__ src,
                      const int* __restrict__ dst,
                      float* __restrict__ out, int E)
{
    const int tid = threadIdx.x;
    const int e0  = blockIdx.x * EPB + tid;

    int eid[EPT], uoff[EPT], voff[EPT];
    #pragma unroll
    for (int k = 0; k < EPT; ++k) {
        const int e = e0 + k * BLOCK;
        eid[k] = e;
        const int es = (e < E) ? e : 0;        // clamp tail: loads harmless
        uoff[k] = src[es] * D;                 // < 6.4M, fits int
        voff[k] = dst[es] * D;
    }

    float acc[EPT][R];
    #pragma unroll
    for (int k = 0; k < EPT; ++k)
        #pragma unroll
        for (int r = 0; r < R; ++r) acc[k][r] = 0.f;

    #pragma unroll
    for (int ph = 0; ph < 2; ++ph) {
        const int fb = ph * FH;

        // vs half-rows register-resident for this phase (128 VGPR)
        float vsr[EPT][FH];
        #pragma unroll
        for (int k = 0; k < EPT; ++k)
            #pragma unroll
            for (int q = 0; q < FH / 4; ++q) {
                const float4 v4 = *reinterpret_cast<const float4*>(
                    ifeat + voff[k] + fb + 4 * q);
                vsr[k][4*q+0] = v4.x; vsr[k][4*q+1] = v4.y;
                vsr[k][4*q+2] = v4.z; vsr[k][4*q+3] = v4.w;
            }

        // manual 1-deep us prefetch: load-use distance = one full dg body
        float4 u4[EPT];
        #pragma unroll
        for (int k = 0; k < EPT; ++k)
            u4[k] = *reinterpret_cast<const float4*>(ufeat + uoff[k]);

        #pragma unroll 1
        for (int dg = 0; dg < D / 4; ++dg) {
            float usr[EPT][4];
            #pragma unroll
            for (int k = 0; k < EPT; ++k) {
                usr[k][0] = u4[k].x; usr[k][1] = u4[k].y;
                usr[k][2] = u4[k].z; usr[k][3] = u4[k].w;
            }
            const int dgn = (dg + 1 < D / 4) ? dg + 1 : 0;   // clamped reload
            #pragma unroll
            for (int k = 0; k < EPT; ++k)
                u4[k] = *reinterpret_cast<const float4*>(ufeat + uoff[k] + 4 * dgn);

            #pragma unroll
            for (int dd = 0; dd < 4; ++dd) {
                #pragma unroll
                for (int r = 0; r < R; ++r) {
                    // wave-uniform P row -> s_load into SGPRs (scalar pipe)
                    const float* __restrict__ p =
                        Ps + ((size_t)(r * D + dg * 4 + dd) * D + fb);
                    float t[EPT];
                    #pragma unroll
                    for (int k = 0; k < EPT; ++k) t[k] = p[0] * vsr[k][0];
                    #pragma unroll
                    for (int f = 1; f < FH; ++f)
                        #pragma unroll
                        for (int k = 0; k < EPT; ++k)
                            t[k] = fmaf(p[f], vsr[k][f], t[k]);   // 4 indep chains
                    #pragma unroll
                    for (int k = 0; k < EPT; ++k)
                        acc[k][r] = fmaf(usr[k][dd], t[k], acc[k][r]);
                }
            }
        }
    }

    // softmax over R + expected rating, predicated store
    #pragma unroll
    for (int k = 0; k < EPT; ++k) {
        if (eid[k] >= E) continue;
        float m = acc[k][0];
        #pragma unroll
        for (int r = 1; r < R; ++r) m = fmaxf(m, acc[k][r]);
        float s = 0.f, num = 0.f;
        #pragma unroll
        for (int r = 0; r < R; ++r) {
            const float pr = expf(acc[k][r] - m);
            s += pr;
            num = fmaf((float)(r + 1), pr, num);
        }
        out[eid[k]] = num / s;
    }
}

extern "C" void kernel_launch(void* const* d_in, const int* in_sizes, int n_in,
                              void* d_out, int out_size, void* d_ws, size_t ws_size,
                              hipStream_t stream)
{
    const float* ufeat = (const float*)d_in[0];
    const float* ifeat = (const float*)d_in[1];
    const float* Ps    = (const float*)d_in[2];
    const int*   src   = (const int*)d_in[3];
    const int*   dst   = (const int*)d_in[4];
    float*       out   = (float*)d_out;
    const int E  = in_sizes[3];
    const int nb = (E + EPB - 1) / EPB;
    hipLaunchKernelGGL(bidecoder_kernel, dim3(nb), dim3(BLOCK), 0, stream,
                       ufeat, ifeat, Ps, src, dst, out, E);
}

// Round 7
// 1811.552 us; speedup vs baseline: 2.7919x; 2.7919x over previous
//
#include <hip/hip_runtime.h>
#include <math.h>

#define D 64
#define R 5
#define EPT 4              // edges/thread: each scalar P value feeds 4 FMAs
#define BLOCK 256
#define EPB (EPT * BLOCK)  // 1024
#define FT 8               // f-tile width (vsr = EPT*FT = 32 VGPR)
#define NPH (D / FT)       // 8 f-phases

// HARD CONSTRAINT (R3/R6): allocator targets 128 VGPR and spills rather than
// exceed it, even with launch_bounds(256,2). Keep live set <= ~120 regs.
__global__ __launch_bounds__(BLOCK, 2)
void bidecoder_kernel(const float* __restrict__ ufeat,
                      const float* __restrict__ ifeat,
                      const float* __restrict__ Ps,
                      const int* __restrict__ src,
                      const int* __restrict__ dst,
                      float* __restrict__ out, int E)
{
    const int tid = threadIdx.x;
    const int e0  = blockIdx.x * EPB + tid;

    int eid[EPT], uoff[EPT], voff[EPT];
    #pragma unroll
    for (int k = 0; k < EPT; ++k) {
        const int e = e0 + k * BLOCK;
        eid[k] = e;
        const int es = (e < E) ? e : 0;        // clamp tail: loads harmless
        uoff[k] = src[es] * D;
        voff[k] = dst[es] * D;
    }

    float acc[EPT][R];
    #pragma unroll
    for (int k = 0; k < EPT; ++k)
        #pragma unroll
        for (int r = 0; r < R; ++r) acc[k][r] = 0.f;

    #pragma unroll 1
    for (int ph = 0; ph < NPH; ++ph) {
        const int fb = ph * FT;

        // vs f-chunk register-resident: 32 VGPR. Re-read per phase (L2/L3-hot).
        float vsr[EPT][FT];
        #pragma unroll
        for (int k = 0; k < EPT; ++k) {
            #pragma unroll
            for (int q = 0; q < FT / 4; ++q) {
                const float4 v4 = *reinterpret_cast<const float4*>(
                    ifeat + voff[k] + fb + 4 * q);
                vsr[k][4*q+0] = v4.x; vsr[k][4*q+1] = v4.y;
                vsr[k][4*q+2] = v4.z; vsr[k][4*q+3] = v4.w;
            }
        }

        // 1-deep us prefetch: load-use distance = one dg body (~1280 cyc > L3 lat)
        float4 un[EPT];
        #pragma unroll
        for (int k = 0; k < EPT; ++k)
            un[k] = *reinterpret_cast<const float4*>(ufeat + uoff[k]);

        #pragma unroll 1
        for (int dg = 0; dg < D / 4; ++dg) {
            float uc[EPT][4];
            #pragma unroll
            for (int k = 0; k < EPT; ++k) {
                uc[k][0] = un[k].x; uc[k][1] = un[k].y;
                uc[k][2] = un[k].z; uc[k][3] = un[k].w;
            }
            const int dgn = (dg + 1 < D / 4) ? dg + 1 : 0;   // clamped reload
            #pragma unroll
            for (int k = 0; k < EPT; ++k)
                un[k] = *reinterpret_cast<const float4*>(ufeat + uoff[k] + 4 * dgn);

            #pragma unroll
            for (int dd = 0; dd < 4; ++dd) {
                #pragma unroll
                for (int r = 0; r < R; ++r) {
                    // wave-uniform P segment (8 floats) -> s_load, scalar pipe
                    const float* __restrict__ p =
                        Ps + ((size_t)(r * D + dg * 4 + dd) * D + fb);
                    float t[EPT];
                    #pragma unroll
                    for (int k = 0; k < EPT; ++k) t[k] = p[0] * vsr[k][0];
                    #pragma unroll
                    for (int f = 1; f < FT; ++f)
                        #pragma unroll
                        for (int k = 0; k < EPT; ++k)
                            t[k] = fmaf(p[f], vsr[k][f], t[k]);  // 4 indep chains
                    #pragma unroll
                    for (int k = 0; k < EPT; ++k)
                        acc[k][r] = fmaf(uc[k][dd], t[k], acc[k][r]);
                }
            }
        }
    }

    // softmax over R + expected rating, predicated store
    #pragma unroll
    for (int k = 0; k < EPT; ++k) {
        if (eid[k] >= E) continue;
        float m = acc[k][0];
        #pragma unroll
        for (int r = 1; r < R; ++r) m = fmaxf(m, acc[k][r]);
        float s = 0.f, num = 0.f;
        #pragma unroll
        for (int r = 0; r < R; ++r) {
            const float pr = expf(acc[k][r] - m);
            s += pr;
            num = fmaf((float)(r + 1), pr, num);
        }
        out[eid[k]] = num / s;
    }
}

extern "C" void kernel_launch(void* const* d_in, const int* in_sizes, int n_in,
                              void* d_out, int out_size, void* d_ws, size_t ws_size,
                              hipStream_t stream)
{
    const float* ufeat = (const float*)d_in[0];
    const float* ifeat = (const float*)d_in[1];
    const float* Ps    = (const float*)d_in[2];
    const int*   src   = (const int*)d_in[3];
    const int*   dst   = (const int*)d_in[4];
    float*       out   = (float*)d_out;
    const int E  = in_sizes[3];
    const int nb = (E + EPB - 1) / EPB;
    hipLaunchKernelGGL(bidecoder_kernel, dim3(nb), dim3(BLOCK), 0, stream,
                       ufeat, ifeat, Ps, src, dst, out, E);
}

// Round 8
// 547.213 us; speedup vs baseline: 9.2425x; 3.3105x over previous
//
#include <hip/hip_runtime.h>
#include <math.h>

#define D 64
#define R 5
#define BLOCK 256
#define NBLOCKS 512
#define WPB (BLOCK / 64)

typedef __attribute__((ext_vector_type(8))) short short8;
typedef __attribute__((ext_vector_type(4))) float f32x4;

__device__ __forceinline__ unsigned short f2bf(float x) {
    unsigned u = __builtin_bit_cast(unsigned, x);
    u = (u + 0x7FFFu + ((u >> 16) & 1u)) >> 16;   // RNE
    return (unsigned short)u;
}
__device__ __forceinline__ float bf2f(unsigned short h) {
    unsigned u = ((unsigned)h) << 16;
    return __builtin_bit_cast(float, u);
}

// scores[e][r] = us[e]^T P_r vs[e]; Y_r = P_r * vs_tile via MFMA (M=d, N=edge, K=f),
// then score = sum_d us[d,e]*Y[d,e] (in-lane Hadamard + xor-shuffle reduce).
// P staged per-block in LDS as bf16 hi/lo in fragment-ready layout:
//   frag group fb = (p*R + r)*2*4 + s*4 + Mt ; element fb*512 + lane*8 + j
//   lane = (d&15) | (g<<4), f = s*32 + g*8 + j  (same k-mapping used for B -> HW k-order cancels)
__global__ __launch_bounds__(BLOCK, 2)
void bidecoder_mfma(const float* __restrict__ ufeat,
                    const float* __restrict__ ifeat,
                    const float* __restrict__ Ps,
                    const int* __restrict__ src,
                    const int* __restrict__ dst,
                    float* __restrict__ out,
                    int E, int NT, int TPB)
{
    __shared__ short plds[40960];   // 80 KB: [p][r][s][Mt][lane][j] bf16

    const int tid = threadIdx.x;

    // ---- one-time P staging: fp32 -> bf16 hi/lo fragments ----
    for (int i = tid; i < R * D * D; i += BLOCK) {
        const int r = i >> 12, d = (i >> 6) & 63, f = i & 63;
        const float val = Ps[i];
        const unsigned short hi = f2bf(val);
        const unsigned short lo = f2bf(val - bf2f(hi));
        const int s = f >> 5, g = (f >> 3) & 3, j = f & 7;
        const int Mt = d >> 4;
        const int lane = (d & 15) | (g << 4);
        const int slot = lane * 8 + j;
        const int fbH = (r * 2 + s) * 4 + Mt;          // p=0
        plds[fbH * 512 + slot]              = (short)hi;
        plds[(fbH + R * 8) * 512 + slot]    = (short)lo;   // p=1 offset = R*2*4
    }
    __syncthreads();

    const int l  = tid & 63;
    const int wv = tid >> 6;
    const int li = l & 15;
    const int lg = l >> 4;

    const int t0 = blockIdx.x * TPB;
    int t1 = t0 + TPB; if (t1 > NT) t1 = NT;

    for (int t = t0 + wv; t < t1; t += WPB) {
        const int e  = t * 16 + li;
        const int es = (e < E) ? e : (E - 1);      // clamp tail, store predicated
        const int ur = src[es], vr = dst[es];

        const float* __restrict__ vrow = ifeat + (size_t)vr * D;
        const float* __restrict__ urow = ufeat + (size_t)ur * D;

        // gather vs (one-shot, 64 B/lane): f = s*32 + lg*8 + j
        float vsf[2][8];
        #pragma unroll
        for (int s = 0; s < 2; ++s) {
            const float4 a = *reinterpret_cast<const float4*>(vrow + s * 32 + lg * 8);
            const float4 b = *reinterpret_cast<const float4*>(vrow + s * 32 + lg * 8 + 4);
            vsf[s][0] = a.x; vsf[s][1] = a.y; vsf[s][2] = a.z; vsf[s][3] = a.w;
            vsf[s][4] = b.x; vsf[s][5] = b.y; vsf[s][6] = b.z; vsf[s][7] = b.w;
        }
        // gather us for Hadamard (C-layout aligned): d = Mt*16 + lg*4 + j
        float usf[4][4];
        #pragma unroll
        for (int Mt = 0; Mt < 4; ++Mt) {
            const float4 a = *reinterpret_cast<const float4*>(urow + Mt * 16 + lg * 4);
            usf[Mt][0] = a.x; usf[Mt][1] = a.y; usf[Mt][2] = a.z; usf[Mt][3] = a.w;
        }

        // split vs into bf16 hi/lo B-fragments
        short8 vhi[2], vlo[2];
        #pragma unroll
        for (int s = 0; s < 2; ++s)
            #pragma unroll
            for (int j = 0; j < 8; ++j) {
                const float x = vsf[s][j];
                const unsigned short h = f2bf(x);
                vhi[s][j] = (short)h;
                vlo[s][j] = (short)f2bf(x - bf2f(h));
            }

        float scores[R];
        #pragma unroll
        for (int r = 0; r < R; ++r) {
            f32x4 acc[4] = { {0,0,0,0},{0,0,0,0},{0,0,0,0},{0,0,0,0} };
            #pragma unroll
            for (int s = 0; s < 2; ++s) {
                #pragma unroll
                for (int Mt = 0; Mt < 4; ++Mt) {
                    const int fbH = (r * 2 + s) * 4 + Mt;
                    const short8 aHi = *reinterpret_cast<const short8*>(&plds[fbH * 512 + l * 8]);
                    const short8 aLo = *reinterpret_cast<const short8*>(&plds[(fbH + R * 8) * 512 + l * 8]);
                    acc[Mt] = __builtin_amdgcn_mfma_f32_16x16x32_bf16(aHi, vhi[s], acc[Mt], 0, 0, 0);
                    acc[Mt] = __builtin_amdgcn_mfma_f32_16x16x32_bf16(aLo, vhi[s], acc[Mt], 0, 0, 0);
                    acc[Mt] = __builtin_amdgcn_mfma_f32_16x16x32_bf16(aHi, vlo[s], acc[Mt], 0, 0, 0);
                }
            }
            // Hadamard with us + reduce over the 4 lane-groups (same edge)
            float part = 0.f;
            #pragma unroll
            for (int Mt = 0; Mt < 4; ++Mt)
                #pragma unroll
                for (int j = 0; j < 4; ++j)
                    part = fmaf(acc[Mt][j], usf[Mt][j], part);
            part += __shfl_xor(part, 16);
            part += __shfl_xor(part, 32);
            scores[r] = part;
        }

        // softmax over R + expected rating (redundant across lane-groups; lg==0 writes)
        float m = scores[0];
        #pragma unroll
        for (int r = 1; r < R; ++r) m = fmaxf(m, scores[r]);
        float ssum = 0.f, num = 0.f;
        #pragma unroll
        for (int r = 0; r < R; ++r) {
            const float p = expf(scores[r] - m);
            ssum += p;
            num = fmaf((float)(r + 1), p, num);
        }
        if (lg == 0 && e < E) out[e] = num / ssum;
    }
}

extern "C" void kernel_launch(void* const* d_in, const int* in_sizes, int n_in,
                              void* d_out, int out_size, void* d_ws, size_t ws_size,
                              hipStream_t stream)
{
    const float* ufeat = (const float*)d_in[0];
    const float* ifeat = (const float*)d_in[1];
    const float* Ps    = (const float*)d_in[2];
    const int*   src   = (const int*)d_in[3];
    const int*   dst   = (const int*)d_in[4];
    float*       out   = (float*)d_out;
    const int E   = in_sizes[3];
    const int NT  = (E + 15) / 16;
    const int TPB = (NT + NBLOCKS - 1) / NBLOCKS;
    hipLaunchKernelGGL(bidecoder_mfma, dim3(NBLOCKS), dim3(BLOCK), 0, stream,
                       ufeat, ifeat, Ps, src, dst, out, E, NT, TPB);
}